// Round 9
// baseline (1005.394 us; speedup 1.0000x reference)
//
#include <hip/hip_runtime.h>
#include <stdint.h>

typedef unsigned int   uint32;
typedef unsigned short ushortT;
typedef short bf16x8 __attribute__((ext_vector_type(8)));
typedef float f32x4  __attribute__((ext_vector_type(4)));

#define T_REAL 100

// ---- workspace layout (unchanged) ----
#define W1S 0          // 3 x [128][256] bf16
#define W2S 98304      // 3 x [64][128]
#define W3S 122880     // 3 x [32][64]
#define WOS 129024     // 3 x [16][32] (rows 2..15 zero)
#define B1F 65280      // float offsets
#define B2F 65408
#define B3F 65472
#define BOF 65504

// ---- LDS layout (bytes), total 31232 -> 5 blocks/CU ----
// u    [16 t][260 n] f32 = 16640   (single buffer reused by every layer)
// mk   [8 w][4 s][100 t] u32 = 12800 (input spike bits, persistent)
// s1mk [4 w][4 s][16 t] u32 = 1024   (layer-1 spike bits)
// s2mk [2 w][4 s][16 t] u32 = 512
// s3mk [4 s][16 t] u32 = 256
#define U_B   0
#define MK_B  16640
#define S1_B  29440
#define S2_B  30464
#define S3_B  30976
#define LDS_BYTES 31232
#define USTR  260

#define MFMA(a,b,c) __builtin_amdgcn_mfma_f32_16x16x32_bf16(a,b,c,0,0,0)

__device__ __forceinline__ ushortT bf16rne(float x) {
    uint32 u = __float_as_uint(x);
    return (ushortT)((u + 0x7FFFu + ((u >> 16) & 1u)) >> 16);
}
__device__ __forceinline__ void split3(float w, ushortT& a, ushortT& b, ushortT& c) {
    a = bf16rne(w); float fa = __uint_as_float((uint32)a << 16);
    float r1 = w - fa;
    b = bf16rne(r1); float fb = __uint_as_float((uint32)b << 16);
    float r2 = r1 - fb;
    c = bf16rne(r2);
}

// 8 spike bits -> bf16x8 {0,1} fragment
__device__ __forceinline__ bf16x8 expand8(uint32 b) {
    union { uint32 u[4]; bf16x8 v; } cv;
    cv.u[0] = ((b & 1u)   ? 0x3F80u : 0u) | ((b & 2u)   ? 0x3F800000u : 0u);
    cv.u[1] = ((b & 4u)   ? 0x3F80u : 0u) | ((b & 8u)   ? 0x3F800000u : 0u);
    cv.u[2] = ((b & 16u)  ? 0x3F80u : 0u) | ((b & 32u)  ? 0x3F800000u : 0u);
    cv.u[3] = ((b & 64u)  ? 0x3F80u : 0u) | ((b & 128u) ? 0x3F800000u : 0u);
    return cv.v;
}

__global__ void prep_w(const float* __restrict__ W1, const float* __restrict__ W2,
                       const float* __restrict__ W3, const float* __restrict__ Wo,
                       const float* __restrict__ bn0g, const float* __restrict__ bn0v,
                       const float* __restrict__ bn1g, const float* __restrict__ bn1v,
                       const float* __restrict__ bn2g, const float* __restrict__ bn2v,
                       const float* __restrict__ bn3g, const float* __restrict__ bn3v,
                       ushortT* __restrict__ wsS)
{
    int idx = blockIdx.x * 256 + threadIdx.x;
    float w; int base, size, off;
    if (idx < 32768) {
        int h = idx >> 8, f = idx & 255;
        float A = bn0g[f] / sqrtf(bn0v[f] + 1e-5f);
        float G = bn1g[h] / sqrtf(bn1v[h] + 1e-5f);
        w = W1[idx] * A * G; base = W1S; size = 32768; off = idx;
    } else if (idx < 40960) {
        int r = idx - 32768; int h = r >> 7;
        float G = bn2g[h] / sqrtf(bn2v[h] + 1e-5f);
        w = W2[r] * G; base = W2S; size = 8192; off = r;
    } else if (idx < 43008) {
        int r = idx - 40960; int h = r >> 6;
        float G = bn3g[h] / sqrtf(bn3v[h] + 1e-5f);
        w = W3[r] * G; base = W3S; size = 2048; off = r;
    } else if (idx < 43520) {
        int r = idx - 43008; int o = r >> 5, k = r & 31;
        w = (o < 2) ? Wo[o * 32 + k] : 0.f;
        base = WOS; size = 512; off = r;
    } else return;
    ushortT a, b, c; split3(w, a, b, c);
    wsS[base + off] = a; wsS[base + size + off] = b; wsS[base + 2 * size + off] = c;
}

__global__ void prep_bias(const float* __restrict__ bn0g, const float* __restrict__ bn0b,
                          const float* __restrict__ bn0m, const float* __restrict__ bn0v,
                          const float* __restrict__ b1,   const float* __restrict__ W1,
                          const float* __restrict__ bn1g, const float* __restrict__ bn1b,
                          const float* __restrict__ bn1m, const float* __restrict__ bn1v,
                          const float* __restrict__ b2,   const float* __restrict__ bn2g,
                          const float* __restrict__ bn2b, const float* __restrict__ bn2m,
                          const float* __restrict__ bn2v,
                          const float* __restrict__ b3,   const float* __restrict__ bn3g,
                          const float* __restrict__ bn3b, const float* __restrict__ bn3m,
                          const float* __restrict__ bn3v,
                          const float* __restrict__ bo,   float* __restrict__ wsF)
{
    __shared__ float Cs[256];
    const int tid = threadIdx.x;
    {
        float A = bn0g[tid] / sqrtf(bn0v[tid] + 1e-5f);
        Cs[tid] = bn0b[tid] - bn0m[tid] * A;
    }
    __syncthreads();
    if (tid < 128) {
        float G  = bn1g[tid] / sqrtf(bn1v[tid] + 1e-5f);
        float Bn = bn1b[tid] - bn1m[tid] * G;
        float s  = b1[tid];
        const float* wr = W1 + tid * 256;
        for (int f = 0; f < 256; ++f) s = fmaf(wr[f], Cs[f], s);
        wsF[B1F + tid] = G * s + Bn;
    }
    if (tid < 64) {
        float G = bn2g[tid] / sqrtf(bn2v[tid] + 1e-5f);
        wsF[B2F + tid] = G * b2[tid] + (bn2b[tid] - bn2m[tid] * G);
    }
    if (tid < 32) {
        float G = bn3g[tid] / sqrtf(bn3v[tid] + 1e-5f);
        wsF[B3F + tid] = G * b3[tid] + (bn3b[tid] - bn3m[tid] * G);
    }
    if (tid < 2) wsF[BOF + tid] = bo[tid];
}

__global__ __launch_bounds__(256, 5) void snn_main(
    const float* __restrict__ xin,
    const ushortT* __restrict__ wsS,
    const float* __restrict__ wsF,
    float* __restrict__ out)
{
    __shared__ uint4 ldsq[LDS_BYTES / 16];
    char* lds = (char*)ldsq;
    float*  ud  = (float*)(lds + U_B);
    uint32* mkd = (uint32*)(lds + MK_B);
    uint32* s1d = (uint32*)(lds + S1_B);
    uint32* s2d = (uint32*)(lds + S2_B);
    uint32* s3d = (uint32*)(lds + S3_B);

    const int tid  = threadIdx.x;
    const int lane = tid & 63;
    const int wvu  = __builtin_amdgcn_readfirstlane(tid >> 6);
    const int lr   = lane & 15;    // MFMA row/col within tile
    const int lg   = lane >> 4;    // MFMA k-group
    const int b0   = blockIdx.x * 4;

    // ---- stage input bitmask once: mk[w][s][t], w = f>>5 ----
    {
        const int fg = wvu;                          // features fg*64..+63
        const int sh = (lane >> 5) * 32;
        for (int s = 0; s < 4; ++s) {
            const float* rp = xin + ((size_t)(b0 + s) * 256 + fg * 64 + lane) * T_REAL;
            uint32* wr = mkd + (fg * 2 + (lane >> 5)) * 400 + s * 100;
#pragma unroll 5
            for (int q = 0; q < 25; ++q) {
                float4 v = *(const float4*)(rp + q * 4);
                unsigned long long bx = __ballot(v.x > 0.5f);
                unsigned long long by = __ballot(v.y > 0.5f);
                unsigned long long bz = __ballot(v.z > 0.5f);
                unsigned long long bw = __ballot(v.w > 0.5f);
                if ((lane & 31) == 0) {
                    *(uint4*)(wr + q * 4) = make_uint4((uint32)(bx >> sh), (uint32)(by >> sh),
                                                      (uint32)(bz >> sh), (uint32)(bw >> sh));
                }
            }
        }
    }

    // persistent LIF states
    float v1h[2] = {0.f, 0.f}, i1h[2] = {0.f, 0.f}; // L1: (s=tid>>6, h = hb*64 + (tid&63))
    float v2 = 0.f, i2 = 0.f;                        // L2: (s=tid>>6, h=tid&63)
    float v3 = 0.f, i3 = 0.f;                        // L3: tid<128 -> (s=tid>>5, h=tid&31)
    float vo = 0.f, io = 0.f, aspk = 0.f;            // out: tid<8

#pragma unroll 1
    for (int w = 0; w < 7; ++w) {
        const int t0 = w * 16;
        __syncthreads();   // staging done (w=0) / prev LIFout u-reads done

        // ================= L1 in two h-halves =================
#pragma unroll
        for (int hb = 0; hb < 2; ++hb) {
            {   // ---- GEMM half: [64 x 256] x [256 x 64], wave = 16 cols ----
                const int cb = wvu * 16;
                const int hB = hb * 64 + cb;
                const float bia = wsF[B1F + hB + lr];
                f32x4 acc[4];
#pragma unroll
                for (int rt = 0; rt < 4; ++rt) acc[rt] = (f32x4){bia, bia, bia, bia};
                const int tt = t0 + lr;
                const int ttc = (tt < T_REAL) ? tt : (T_REAL - 1);
#pragma unroll 2
                for (int ks = 0; ks < 8; ++ks) {
                    const int koff = ks * 32 + lg * 8;
                    const ushortT* wb = wsS + W1S + (hB + lr) * 256 + koff;
                    bf16x8 Bh = *(const bf16x8*)(wb);
                    bf16x8 Bm = *(const bf16x8*)(wb + 32768);
                    bf16x8 Bl = *(const bf16x8*)(wb + 65536);
#pragma unroll
                    for (int rt = 0; rt < 4; ++rt) {
                        uint32 m = mkd[ks * 400 + rt * 100 + ttc];
                        if (tt >= T_REAL) m = 0;
                        bf16x8 A = expand8((m >> (lg * 8)) & 0xFFu);
                        acc[rt] = MFMA(A, Bh, acc[rt]);
                        acc[rt] = MFMA(A, Bm, acc[rt]);
                        acc[rt] = MFMA(A, Bl, acc[rt]);
                    }
                }
#pragma unroll
                for (int rt = 0; rt < 4; ++rt)
#pragma unroll
                    for (int j = 0; j < 4; ++j)
                        ud[(lg * 4 + j) * USTR + rt * 64 + cb + lr] = acc[rt][j];
            }
            __syncthreads();   // u ready

            {   // ---- LIF half: 256 neurons, 1/thread; ballot-pack bits ----
                float uu[16];
#pragma unroll
                for (int t = 0; t < 16; ++t) uu[t] = ud[t * USTR + tid];
                float v = v1h[hb], ii = i1h[hb];
#pragma unroll
                for (int t = 0; t < 16; ++t) {
                    float vd = v + 0.1f * ((0.0f - v) + ii);
                    bool z = vd > 1.0f;
                    v = z ? 0.0f : vd;
                    ii = (ii - 0.2f * ii) + uu[t];
                    unsigned long long bz = __ballot(z);
                    if (lane == 0)  s1d[(hb * 2 + 0) * 64 + wvu * 16 + t] = (uint32)bz;
                    if (lane == 32) s1d[(hb * 2 + 1) * 64 + wvu * 16 + t] = (uint32)(bz >> 32);
                }
                v1h[hb] = v; i1h[hb] = ii;
            }
            __syncthreads();   // u free (next half / L2), s1 bits ready
        }

        // ================= L2: [64 x 128] x [128 x 64] =================
        {
            const int cb = wvu * 16;
            const float bia = wsF[B2F + cb + lr];
            f32x4 acc[4];
#pragma unroll
            for (int rt = 0; rt < 4; ++rt) acc[rt] = (f32x4){bia, bia, bia, bia};
#pragma unroll 2
            for (int ks = 0; ks < 4; ++ks) {
                const int koff = ks * 32 + lg * 8;
                const ushortT* wb = wsS + W2S + (cb + lr) * 128 + koff;
                bf16x8 Bh = *(const bf16x8*)(wb);
                bf16x8 Bm = *(const bf16x8*)(wb + 8192);
                bf16x8 Bl = *(const bf16x8*)(wb + 16384);
#pragma unroll
                for (int rt = 0; rt < 4; ++rt) {
                    uint32 m = s1d[ks * 64 + rt * 16 + lr];
                    bf16x8 A = expand8((m >> (lg * 8)) & 0xFFu);
                    acc[rt] = MFMA(A, Bh, acc[rt]);
                    acc[rt] = MFMA(A, Bm, acc[rt]);
                    acc[rt] = MFMA(A, Bl, acc[rt]);
                }
            }
#pragma unroll
            for (int rt = 0; rt < 4; ++rt)
#pragma unroll
                for (int j = 0; j < 4; ++j)
                    ud[(lg * 4 + j) * USTR + rt * 64 + cb + lr] = acc[rt][j];
        }
        __syncthreads();

        // ---- LIF2: 256 neurons ----
        {
            float uu[16];
#pragma unroll
            for (int t = 0; t < 16; ++t) uu[t] = ud[t * USTR + tid];
            float v = v2, ii = i2;
#pragma unroll
            for (int t = 0; t < 16; ++t) {
                float vd = v + 0.1f * ((0.0f - v) + ii);
                bool z = vd > 1.0f;
                v = z ? 0.0f : vd;
                ii = (ii - 0.2f * ii) + uu[t];
                unsigned long long bz = __ballot(z);
                if (lane == 0)  s2d[0 * 64 + wvu * 16 + t] = (uint32)bz;
                if (lane == 32) s2d[1 * 64 + wvu * 16 + t] = (uint32)(bz >> 32);
            }
            v2 = v; i2 = ii;
        }
        __syncthreads();

        // ================= L3: [64 x 64] x [64 x 32], waves 2x2 =================
        {
            const int rhu = wvu >> 1, chu = wvu & 1;
            const float bia = wsF[B3F + chu * 16 + lr];
            f32x4 acc[2];
            acc[0] = (f32x4){bia, bia, bia, bia};
            acc[1] = (f32x4){bia, bia, bia, bia};
#pragma unroll
            for (int ks = 0; ks < 2; ++ks) {
                const int koff = ks * 32 + lg * 8;
                const ushortT* wb = wsS + W3S + (chu * 16 + lr) * 64 + koff;
                bf16x8 Bh = *(const bf16x8*)(wb);
                bf16x8 Bm = *(const bf16x8*)(wb + 2048);
                bf16x8 Bl = *(const bf16x8*)(wb + 4096);
#pragma unroll
                for (int r = 0; r < 2; ++r) {
                    uint32 m = s2d[ks * 64 + (rhu * 2 + r) * 16 + lr];
                    bf16x8 A = expand8((m >> (lg * 8)) & 0xFFu);
                    acc[r] = MFMA(A, Bh, acc[r]);
                    acc[r] = MFMA(A, Bm, acc[r]);
                    acc[r] = MFMA(A, Bl, acc[r]);
                }
            }
#pragma unroll
            for (int r = 0; r < 2; ++r)
#pragma unroll
                for (int j = 0; j < 4; ++j)
                    ud[(lg * 4 + j) * USTR + (rhu * 2 + r) * 32 + chu * 16 + lr] = acc[r][j];
        }
        __syncthreads();

        // ---- LIF3: 128 neurons (waves 0,1) ----
        if (tid < 128) {
            float uu[16];
#pragma unroll
            for (int t = 0; t < 16; ++t) uu[t] = ud[t * USTR + tid];
            float v = v3, ii = i3;
#pragma unroll
            for (int t = 0; t < 16; ++t) {
                float vd = v + 0.1f * ((0.0f - v) + ii);
                bool z = vd > 1.0f;
                v = z ? 0.0f : vd;
                ii = (ii - 0.2f * ii) + uu[t];
                unsigned long long bz = __ballot(z);
                if (lane == 0)  s3d[(wvu * 2 + 0) * 16 + t] = (uint32)bz;
                if (lane == 32) s3d[(wvu * 2 + 1) * 16 + t] = (uint32)(bz >> 32);
            }
            v3 = v; i3 = ii;
        }
        __syncthreads();

        // ================= Lout: [64 x 32] x [32 x 16(2 real)] =================
        {
            const float bia = (lr < 2) ? wsF[BOF + lr] : 0.f;
            f32x4 acc = (f32x4){bia, bia, bia, bia};
            const int koff = lg * 8;
            const ushortT* wb = wsS + WOS + lr * 32 + koff;
            bf16x8 Bh = *(const bf16x8*)(wb);
            bf16x8 Bm = *(const bf16x8*)(wb + 512);
            bf16x8 Bl = *(const bf16x8*)(wb + 1024);
            uint32 m = s3d[wvu * 16 + lr];
            bf16x8 A = expand8((m >> (lg * 8)) & 0xFFu);
            acc = MFMA(A, Bh, acc);
            acc = MFMA(A, Bm, acc);
            acc = MFMA(A, Bl, acc);
            if (lr < 2) {
#pragma unroll
                for (int j = 0; j < 4; ++j)
                    ud[(lg * 4 + j) * USTR + wvu * 2 + lr] = acc[j];
            }
        }
        __syncthreads();

        // ---- LIF out + accumulate (t<100 guard) ----
        if (tid < 8) {
            float v = vo, ii = io, a = aspk;
#pragma unroll
            for (int t = 0; t < 16; ++t) {
                float vd = v + 0.1f * ((0.0f - v) + ii);
                bool z = vd > 1.0f;
                v = z ? 0.0f : vd;
                ii = (ii - 0.2f * ii) + ud[t * USTR + tid];
                if (t0 + t < T_REAL) a += z ? 1.0f : 0.0f;
            }
            vo = v; io = ii; aspk = a;
        }
        // loop-top barrier protects u before next window's L1a scatter
    }

    if (tid < 8) out[(size_t)(b0 + (tid >> 1)) * 2 + (tid & 1)] = aspk;
}

extern "C" void kernel_launch(void* const* d_in, const int* in_sizes, int n_in,
                              void* d_out, int out_size, void* d_ws, size_t ws_size,
                              hipStream_t stream)
{
    const float* x    = (const float*)d_in[0];
    const float* bn0g = (const float*)d_in[1];
    const float* bn0b = (const float*)d_in[2];
    const float* bn0m = (const float*)d_in[3];
    const float* bn0v = (const float*)d_in[4];
    const float* W1   = (const float*)d_in[5];
    const float* b1   = (const float*)d_in[6];
    const float* bn1g = (const float*)d_in[7];
    const float* bn1b = (const float*)d_in[8];
    const float* bn1m = (const float*)d_in[9];
    const float* bn1v = (const float*)d_in[10];
    const float* W2   = (const float*)d_in[11];
    const float* b2   = (const float*)d_in[12];
    const float* bn2g = (const float*)d_in[13];
    const float* bn2b = (const float*)d_in[14];
    const float* bn2m = (const float*)d_in[15];
    const float* bn2v = (const float*)d_in[16];
    const float* W3   = (const float*)d_in[17];
    const float* b3   = (const float*)d_in[18];
    const float* bn3g = (const float*)d_in[19];
    const float* bn3b = (const float*)d_in[20];
    const float* bn3m = (const float*)d_in[21];
    const float* bn3v = (const float*)d_in[22];
    const float* Wo   = (const float*)d_in[23];
    const float* bo   = (const float*)d_in[24];

    ushortT* wsS = (ushortT*)d_ws;
    float*   wsF = (float*)d_ws;
    float*   pout = (float*)d_out;

    prep_w<<<170, 256, 0, stream>>>(W1, W2, W3, Wo, bn0g, bn0v, bn1g, bn1v,
                                    bn2g, bn2v, bn3g, bn3v, wsS);
    prep_bias<<<1, 256, 0, stream>>>(bn0g, bn0b, bn0m, bn0v, b1, W1,
                                     bn1g, bn1b, bn1m, bn1v,
                                     b2, bn2g, bn2b, bn2m, bn2v,
                                     b3, bn3g, bn3b, bn3m, bn3v, bo, wsF);
    snn_main<<<1024, 256, 0, stream>>>(x, wsS, wsF, pout);
}